// Round 4
// baseline (956.231 us; speedup 1.0000x reference)
//
#include <hip/hip_runtime.h>
#include <stdint.h>

#define L_DIM 2048
#define B_DIM 16
#define D_DIM 1024
#define M_DIM 32768              // L*B
#define K_DIM 1024               // D
#define N_DIM 3072               // 3D
#define SCALE_X 1.7320508075688772f

typedef __attribute__((ext_vector_type(8))) short short8;
typedef __attribute__((ext_vector_type(4))) float f32x4;

__device__ __forceinline__ float bf2f(uint32_t b) {
    union { uint32_t u; float f; } v; v.u = b << 16; return v.f;
}
__device__ __forceinline__ uint16_t f2bf(float f) {
    union { float f; uint32_t u; } v; v.f = f;
    uint32_t u = v.u;
    return (uint16_t)((u + 0x7FFFu + ((u >> 16) & 1u)) >> 16);  // RNE
}
__device__ __forceinline__ void async_copy16(const void* g, void* l) {
    __builtin_amdgcn_global_load_lds(
        (const __attribute__((address_space(1))) unsigned int*)g,
        (__attribute__((address_space(3))) unsigned int*)l, 16, 0, 0);
}

// ---- prep: weight (K x N fp32) -> Wt (N x K bf16), i.e. B^T ----
__global__ void prep_w_kernel(const float* __restrict__ w, uint16_t* __restrict__ wt) {
    int i = blockIdx.x * 256 + threadIdx.x;       // over K*N, coalesced read
    int k = i / N_DIM;
    int n = i - k * N_DIM;
    wt[n * K_DIM + k] = f2bf(w[i]);
}

// ---- prep (full path): x fp32 -> xb bf16 ----
__global__ void convert_x_kernel(const float* __restrict__ x, uint16_t* __restrict__ xb) {
    int i = blockIdx.x * 256 + threadIdx.x;       // over M*K/4
    float4 v = ((const float4*)x)[i];
    ushort4 o;
    o.x = f2bf(v.x); o.y = f2bf(v.y); o.z = f2bf(v.z); o.w = f2bf(v.w);
    ((ushort4*)xb)[i] = o;
}

// ---- GEMM: u01 plane (d_out alias) + {u2,xp} or u2-only plane (ws) ----
// 128x128 tile, BK=32, 4 waves x 4x4 frags of 16x16x32 bf16 MFMA.
// USE_XB: A staged via global_load_lds from pre-converted bf16 xb.
// PACK23: epilogue writes u23 = {u2 | f2bf(SCALE_X*x)<<16} else u2p (2B).
template<bool USE_XB, bool PACK23>
__global__ void __launch_bounds__(256)
gemm_kernel(const float* __restrict__ A32,    // x fp32, M x K
            const uint16_t* __restrict__ Axb, // xb bf16, M x K (full path)
            const uint16_t* __restrict__ Bt,  // Wt bf16, N x K
            uint16_t* __restrict__ u01,       // M x D x 2 — aliases d_out h region
            uint32_t* __restrict__ u23,       // M x D (PACK23)
            uint16_t* __restrict__ u2p)       // M x D (!PACK23)
{
    __shared__ uint16_t As[128 * 32];
    __shared__ uint16_t Bs[128 * 32];

    // supertile swizzle: groups of 8 m-tiles x all 24 n-tiles
    int bid = blockIdx.x;
    int mg = bid / 192;
    int tt = bid - mg * 192;
    int ntile = tt >> 3;
    int mtile = mg * 8 + (tt & 7);
    int m0 = mtile * 128;
    int n0 = ntile * 128;

    int t = threadIdx.x;
    int lane = t & 63;
    int w = t >> 6;
    int wm = (w >> 1) * 64;
    int wn = (w & 1) * 64;

    f32x4 acc[4][4] = {};

    int frow = lane & 15;
    int fk = (lane >> 4) * 8;

    for (int kt = 0; kt < K_DIM; kt += 32) {
        if (USE_XB) {
            // A: 2 async 16B chunks/thread, LDS dest = wave-uniform + lane*16
#pragma unroll
            for (int c = 0; c < 2; c++) {
                int idx = c * 256 + t;
                int row = idx >> 2;
                int ko = (idx & 3) * 8;
                int ldsbase = (c * 256 + w * 64) * 8;   // elements
                async_copy16(Axb + (size_t)(m0 + row) * K_DIM + kt + ko, As + ldsbase);
            }
        } else {
            // A: fp32 load + convert + ds_write
#pragma unroll
            for (int c = 0; c < 4; c++) {
                int idx = c * 256 + t;
                int row = idx >> 3;
                int ko = (idx & 7) * 4;
                float4 v = *(const float4*)(A32 + (size_t)(m0 + row) * K_DIM + kt + ko);
                ushort4 o;
                o.x = f2bf(v.x); o.y = f2bf(v.y); o.z = f2bf(v.z); o.w = f2bf(v.w);
                *(ushort4*)(As + row * 32 + ko) = o;
            }
        }
        // B: 2 async 16B chunks/thread
#pragma unroll
        for (int c = 0; c < 2; c++) {
            int idx = c * 256 + t;
            int ldsbase = (c * 256 + w * 64) * 8;
            int row = idx >> 2;
            int ko = (idx & 3) * 8;
            async_copy16(Bt + (size_t)(n0 + row) * K_DIM + kt + ko, Bs + ldsbase);
        }
        __syncthreads();

        short8 af[4], bfr[4];
#pragma unroll
        for (int i = 0; i < 4; i++) {
            af[i]  = *(const short8*)(As + (wm + i * 16 + frow) * 32 + fk);
            bfr[i] = *(const short8*)(Bs + (wn + i * 16 + frow) * 32 + fk);
        }
#pragma unroll
        for (int i = 0; i < 4; i++)
#pragma unroll
            for (int j = 0; j < 4; j++)
                acc[i][j] = __builtin_amdgcn_mfma_f32_16x16x32_bf16(af[i], bfr[j], acc[i][j], 0, 0, 0);
        __syncthreads();
    }

    // epilogue: C/D layout col=lane&15, row=(lane>>4)*4+reg  [m89-verified]
    int colf = lane & 15;
    int rowq = (lane >> 4) * 4;
#pragma unroll
    for (int i = 0; i < 4; i++) {
#pragma unroll
        for (int j = 0; j < 4; j++) {
            int gcol = n0 + wn + j * 16 + colf;      // n = 3*d + comp
            int dq = gcol / 3;
            int cm = gcol - dq * 3;
#pragma unroll
            for (int r = 0; r < 4; r++) {
                int grow = m0 + wm + i * 16 + rowq + r;
                uint16_t v = f2bf(acc[i][j][r]);
                if (cm < 2) {
                    u01[(size_t)grow * 2048 + dq * 2 + cm] = v;
                } else if (PACK23) {
                    // pack {u2, xp}; x tile is L2-hot (just streamed by K-loop)
                    float xv = A32[(size_t)grow * K_DIM + dq] * SCALE_X;
                    u23[(size_t)grow * 1024 + dq] = (uint32_t)v | ((uint32_t)f2bf(xv) << 16);
                } else {
                    u2p[(size_t)grow * 1024 + dq] = v;
                }
            }
        }
    }
}

// ---- scan (packed path): 2 loads/step, P=32 deep prefetch ----
// u01 aliases the fp32 h region: same-thread, same 4B/(l,cid), reads run P
// ahead of writes -> race-free (validated round 3).
__global__ void __launch_bounds__(64)
scan2_kernel(const uint32_t* u01,              // M x D of {u0,u1} (aliases out)
             const uint32_t* __restrict__ u23, // M x D of {u2,xp}
             const float* __restrict__ c0,
             const float* __restrict__ wc,
             const float* __restrict__ bias,
             float* out)                       // h (L,B,D) then c_final (B,D)
{
    int cid = blockIdx.x * 64 + threadIdx.x;
    int d = cid & (D_DIM - 1);
    float fw = wc[d], rw = wc[D_DIM + d];
    float fb = bias[d], rb = bias[D_DIM + d];
    float c = c0[cid];

    constexpr int P = 32;
    const int STEP = B_DIM * D_DIM;                // 16384
    uint32_t b01[P], b23[P];
#pragma unroll
    for (int j = 0; j < P; j++) {
        b01[j] = u01[cid + j * STEP];
        b23[j] = u23[cid + j * STEP];
    }

    for (int lb = 0; lb < L_DIM; lb += P) {
#pragma unroll
        for (int j = 0; j < P; j++) {
            int l = lb + j;
            uint32_t v01 = b01[j];
            uint32_t v23 = b23[j];

            int ln = l + P; if (ln > L_DIM - 1) ln = L_DIM - 1;
            int ri = cid + ln * STEP;
            b01[j] = u01[ri];
            b23[j] = u23[ri];

            float u0 = bf2f(v01 & 0xFFFFu);
            float u1 = bf2f(v01 >> 16);
            float u2 = bf2f(v23 & 0xFFFFu);
            float xp = bf2f(v23 >> 16);

            float ef = __expf(-(u1 + fb + c * fw));
            float er = __expf(-(u2 + rb + c * rw));
            float f = __builtin_amdgcn_rcpf(1.0f + ef);
            float r = __builtin_amdgcn_rcpf(1.0f + er);
            c = u0 + (c - u0) * f;
            float h = xp + (c - xp) * r;
            out[l * STEP + cid] = h;
        }
    }
    out[L_DIM * STEP + cid] = c;
}

// ---- scan (fallback, ws-small path): u01 + u2 + fp32 x, P=16 ----
__global__ void __launch_bounds__(64)
scan_kernel(const uint32_t* u01,
            const uint16_t* __restrict__ u2p,
            const float* __restrict__ x,
            const float* __restrict__ c0,
            const float* __restrict__ wc,
            const float* __restrict__ bias,
            float* out)
{
    int cid = blockIdx.x * 64 + threadIdx.x;
    int d = cid & (D_DIM - 1);
    float fw = wc[d], rw = wc[D_DIM + d];
    float fb = bias[d], rb = bias[D_DIM + d];
    float c = c0[cid];

    constexpr int P = 16;
    const int STEP = B_DIM * D_DIM;
    uint32_t b01[P];
    uint16_t b2v[P];
    float bx[P];
#pragma unroll
    for (int j = 0; j < P; j++) {
        b01[j] = u01[cid + j * STEP];
        b2v[j] = u2p[cid + j * STEP];
        bx[j]  = x[cid + j * STEP];
    }
    for (int lb = 0; lb < L_DIM; lb += P) {
#pragma unroll
        for (int j = 0; j < P; j++) {
            int l = lb + j;
            uint32_t v01 = b01[j];
            float u2 = bf2f((uint32_t)b2v[j]);
            float xp = bx[j] * SCALE_X;
            int ln = l + P; if (ln > L_DIM - 1) ln = L_DIM - 1;
            int ri = cid + ln * STEP;
            b01[j] = u01[ri];
            b2v[j] = u2p[ri];
            bx[j]  = x[ri];
            float u0 = bf2f(v01 & 0xFFFFu);
            float u1 = bf2f(v01 >> 16);
            float ef = __expf(-(u1 + fb + c * fw));
            float er = __expf(-(u2 + rb + c * rw));
            float f = __builtin_amdgcn_rcpf(1.0f + ef);
            float r = __builtin_amdgcn_rcpf(1.0f + er);
            c = u0 + (c - u0) * f;
            float h = xp + (c - xp) * r;
            out[l * STEP + cid] = h;
        }
    }
    out[L_DIM * STEP + cid] = c;
}

extern "C" void kernel_launch(void* const* d_in, const int* in_sizes, int n_in,
                              void* d_out, int out_size, void* d_ws, size_t ws_size,
                              hipStream_t stream) {
    const float* x    = (const float*)d_in[0];
    const float* c0   = (const float*)d_in[1];
    const float* w    = (const float*)d_in[2];
    const float* wc   = (const float*)d_in[3];
    const float* bias = (const float*)d_in[4];

    const size_t WT_BYTES  = 6291456;       // 6 MB
    const size_t U23_BYTES = 134217728;     // 128 MB
    const size_t XB_BYTES  = 67108864;      // 64 MB

    uint16_t* wt  = (uint16_t*)d_ws;
    char* p = (char*)d_ws + WT_BYTES;

    uint16_t* u01 = (uint16_t*)d_out;       // aliases h region of d_out
    float* out = (float*)d_out;

    bool mid  = ws_size >= WT_BYTES + U23_BYTES;
    bool full = ws_size >= WT_BYTES + U23_BYTES + XB_BYTES;

    prep_w_kernel<<<(K_DIM * N_DIM) / 256, 256, 0, stream>>>(w, wt);

    if (full) {
        uint32_t* u23 = (uint32_t*)p;
        uint16_t* xb  = (uint16_t*)(p + U23_BYTES);
        convert_x_kernel<<<(M_DIM * K_DIM / 4) / 256, 256, 0, stream>>>(x, xb);
        gemm_kernel<true, true><<<(M_DIM / 128) * (N_DIM / 128), 256, 0, stream>>>(
            x, xb, wt, u01, u23, nullptr);
        scan2_kernel<<<(B_DIM * D_DIM) / 64, 64, 0, stream>>>(
            (const uint32_t*)u01, u23, c0, wc, bias, out);
    } else if (mid) {
        uint32_t* u23 = (uint32_t*)p;
        gemm_kernel<false, true><<<(M_DIM / 128) * (N_DIM / 128), 256, 0, stream>>>(
            x, nullptr, wt, u01, u23, nullptr);
        scan2_kernel<<<(B_DIM * D_DIM) / 64, 64, 0, stream>>>(
            (const uint32_t*)u01, u23, c0, wc, bias, out);
    } else {
        uint16_t* u2p = (uint16_t*)p;
        gemm_kernel<false, false><<<(M_DIM / 128) * (N_DIM / 128), 256, 0, stream>>>(
            x, nullptr, wt, u01, nullptr, u2p);
        scan_kernel<<<(B_DIM * D_DIM) / 64, 64, 0, stream>>>(
            (const uint32_t*)u01, u2p, x, c0, wc, bias, out);
    }
}

// Round 5
// 821.456 us; speedup vs baseline: 1.1641x; 1.1641x over previous
//
#include <hip/hip_runtime.h>
#include <stdint.h>

#define L_DIM 2048
#define B_DIM 16
#define D_DIM 1024
#define M_DIM 32768              // L*B
#define K_DIM 1024               // D
#define N_DIM 3072               // 3D
#define SCALE_X 1.7320508075688772f

typedef __attribute__((ext_vector_type(8))) short short8;
typedef __attribute__((ext_vector_type(4))) float f32x4;

__device__ __forceinline__ float bf2f(uint32_t b) {
    union { uint32_t u; float f; } v; v.u = b << 16; return v.f;
}
__device__ __forceinline__ uint16_t f2bf(float f) {
    union { float f; uint32_t u; } v; v.f = f;
    uint32_t u = v.u;
    return (uint16_t)((u + 0x7FFFu + ((u >> 16) & 1u)) >> 16);  // RNE
}
__device__ __forceinline__ void async_copy16(const void* g, void* l) {
    __builtin_amdgcn_global_load_lds(
        (const __attribute__((address_space(1))) unsigned int*)g,
        (__attribute__((address_space(3))) unsigned int*)l, 16, 0, 0);
}

// ---- prep: weight (K x N fp32) -> Wt (N x K bf16), i.e. B^T ----
__global__ void prep_w_kernel(const float* __restrict__ w, uint16_t* __restrict__ wt) {
    int i = blockIdx.x * 256 + threadIdx.x;       // over K*N, coalesced read
    int k = i / N_DIM;
    int n = i - k * N_DIM;
    wt[n * K_DIM + k] = f2bf(w[i]);
}

// ---- prep: x fp32 -> xb bf16 AND xp=SCALE_X*x into u23 high halves ----
__global__ void prep_x_kernel(const float* __restrict__ x, uint16_t* __restrict__ xb,
                              uint16_t* __restrict__ u23h) {   // = (uint16_t*)u23
    int i = blockIdx.x * 256 + threadIdx.x;       // over M*K/4
    float4 v = ((const float4*)x)[i];
    ushort4 o;
    o.x = f2bf(v.x); o.y = f2bf(v.y); o.z = f2bf(v.z); o.w = f2bf(v.w);
    ((ushort4*)xb)[i] = o;
    int e = i * 4;                                // element index m*1024+d
    u23h[(size_t)e * 2 + 1] = f2bf(v.x * SCALE_X);
    u23h[(size_t)e * 2 + 3] = f2bf(v.y * SCALE_X);
    u23h[(size_t)e * 2 + 5] = f2bf(v.z * SCALE_X);
    u23h[(size_t)e * 2 + 7] = f2bf(v.w * SCALE_X);
}

// ---- GEMM: u01 plane (d_out alias) + u2 (low half of u23 / contiguous) ----
// 128x128 tile, BK=32, 4 waves x 4x4 frags of 16x16x32 bf16 MFMA.
// USE_XB: A staged via global_load_lds from bf16 xb. PACKED: u2 -> u23 lo.
template<bool USE_XB, bool PACKED>
__global__ void __launch_bounds__(256)
gemm_kernel(const float* __restrict__ A32,    // x fp32, M x K (fallback staging)
            const uint16_t* __restrict__ Axb, // xb bf16, M x K
            const uint16_t* __restrict__ Bt,  // Wt bf16, N x K
            uint16_t* __restrict__ u01,       // M x D x 2 — aliases d_out h region
            uint16_t* __restrict__ u2d)       // PACKED: u23 as u16 (stride 2); else M x D
{
    __shared__ uint16_t As[128 * 32];
    __shared__ uint16_t Bs[128 * 32];

    // supertile swizzle: groups of 8 m-tiles x all 24 n-tiles
    int bid = blockIdx.x;
    int mg = bid / 192;
    int tt = bid - mg * 192;
    int ntile = tt >> 3;
    int mtile = mg * 8 + (tt & 7);
    int m0 = mtile * 128;
    int n0 = ntile * 128;

    int t = threadIdx.x;
    int lane = t & 63;
    int w = t >> 6;
    int wm = (w >> 1) * 64;
    int wn = (w & 1) * 64;

    f32x4 acc[4][4] = {};

    int frow = lane & 15;
    int fk = (lane >> 4) * 8;

    for (int kt = 0; kt < K_DIM; kt += 32) {
        if (USE_XB) {
#pragma unroll
            for (int c = 0; c < 2; c++) {
                int idx = c * 256 + t;
                int row = idx >> 2;
                int ko = (idx & 3) * 8;
                int ldsbase = (c * 256 + w * 64) * 8;   // elements
                async_copy16(Axb + (size_t)(m0 + row) * K_DIM + kt + ko, As + ldsbase);
            }
        } else {
#pragma unroll
            for (int c = 0; c < 4; c++) {
                int idx = c * 256 + t;
                int row = idx >> 3;
                int ko = (idx & 7) * 4;
                float4 v = *(const float4*)(A32 + (size_t)(m0 + row) * K_DIM + kt + ko);
                ushort4 o;
                o.x = f2bf(v.x); o.y = f2bf(v.y); o.z = f2bf(v.z); o.w = f2bf(v.w);
                *(ushort4*)(As + row * 32 + ko) = o;
            }
        }
#pragma unroll
        for (int c = 0; c < 2; c++) {
            int idx = c * 256 + t;
            int ldsbase = (c * 256 + w * 64) * 8;
            int row = idx >> 2;
            int ko = (idx & 3) * 8;
            async_copy16(Bt + (size_t)(n0 + row) * K_DIM + kt + ko, Bs + ldsbase);
        }
        __syncthreads();

        short8 af[4], bfr[4];
#pragma unroll
        for (int i = 0; i < 4; i++) {
            af[i]  = *(const short8*)(As + (wm + i * 16 + frow) * 32 + fk);
            bfr[i] = *(const short8*)(Bs + (wn + i * 16 + frow) * 32 + fk);
        }
#pragma unroll
        for (int i = 0; i < 4; i++)
#pragma unroll
            for (int j = 0; j < 4; j++)
                acc[i][j] = __builtin_amdgcn_mfma_f32_16x16x32_bf16(af[i], bfr[j], acc[i][j], 0, 0, 0);
        __syncthreads();
    }

    // epilogue: C/D layout col=lane&15, row=(lane>>4)*4+reg  [m89-verified]
    int colf = lane & 15;
    int rowq = (lane >> 4) * 4;
#pragma unroll
    for (int i = 0; i < 4; i++) {
#pragma unroll
        for (int j = 0; j < 4; j++) {
            int gcol = n0 + wn + j * 16 + colf;      // n = 3*d + comp
            int dq = gcol / 3;
            int cm = gcol - dq * 3;
#pragma unroll
            for (int r = 0; r < 4; r++) {
                int grow = m0 + wm + i * 16 + rowq + r;
                uint16_t v = f2bf(acc[i][j][r]);
                if (cm < 2)      u01[(size_t)grow * 2048 + dq * 2 + cm] = v;
                else if (PACKED) u2d[((size_t)grow * 1024 + dq) * 2] = v;   // low half of u23
                else             u2d[(size_t)grow * 1024 + dq] = v;
            }
        }
    }
}

__device__ __forceinline__ void sru_step(uint32_t v01, uint32_t v23,
                                         float fw, float rw, float fb, float rb,
                                         float& c, float& h) {
    float u0 = bf2f(v01 & 0xFFFFu);
    float u1 = bf2f(v01 >> 16);
    float u2 = bf2f(v23 & 0xFFFFu);
    float xp = bf2f(v23 >> 16);
    float ef = __expf(-(u1 + fb + c * fw));
    float er = __expf(-(u2 + rb + c * rw));
    float f = __builtin_amdgcn_rcpf(1.0f + ef);
    float r = __builtin_amdgcn_rcpf(1.0f + er);
    c = u0 + (c - u0) * f;
    h = xp + (c - xp) * r;
}

// ---- scan: explicit ping-pong double buffer, grouped loads then compute ----
// u01 overlaps out's h region at identical (l,cid) words; every u01[l'] read
// happens >= P steps before the out[l'] write in the SAME thread (~300 instr
// margin), so __restrict__ is safe and lets loads pipeline past stores.
__global__ void __launch_bounds__(64)
scan2_kernel(const uint32_t* __restrict__ u01,
             const uint32_t* __restrict__ u23,
             const float* __restrict__ c0,
             const float* __restrict__ wc,
             const float* __restrict__ bias,
             float* __restrict__ out)
{
    constexpr int P = 16;
    const int STEP = B_DIM * D_DIM;                // 16384
    int cid = blockIdx.x * 64 + threadIdx.x;
    int d = cid & (D_DIM - 1);
    float fw = wc[d], rw = wc[D_DIM + d];
    float fb = bias[d], rb = bias[D_DIM + d];
    float c = c0[cid];

    const uint32_t* p01 = u01 + cid;
    const uint32_t* p23 = u23 + cid;
    uint32_t a01[P], a23[P], b01[P], b23[P];
#pragma unroll
    for (int j = 0; j < P; j++) { a01[j] = p01[(size_t)j * STEP]; a23[j] = p23[(size_t)j * STEP]; }

    for (int lb = 0; lb < L_DIM; lb += 2 * P) {
        int nb = lb + P;
#pragma unroll
        for (int j = 0; j < P; j++) {
            b01[j] = p01[(size_t)(nb + j) * STEP];
            b23[j] = p23[(size_t)(nb + j) * STEP];
        }
#pragma unroll
        for (int j = 0; j < P; j++) {
            float h; sru_step(a01[j], a23[j], fw, rw, fb, rb, c, h);
            out[(size_t)(lb + j) * STEP + cid] = h;
        }
        int nb2 = lb + 2 * P;
#pragma unroll
        for (int j = 0; j < P; j++) {
            int l = nb2 + j; if (l > L_DIM - 1) l = L_DIM - 1;
            a01[j] = p01[(size_t)l * STEP];
            a23[j] = p23[(size_t)l * STEP];
        }
#pragma unroll
        for (int j = 0; j < P; j++) {
            float h; sru_step(b01[j], b23[j], fw, rw, fb, rb, c, h);
            out[(size_t)(nb + j) * STEP + cid] = h;
        }
    }
    out[(size_t)L_DIM * STEP + cid] = c;
}

// ---- fallback scan (small ws): 3 streams, P=16 (round-3 verified) ----
__global__ void __launch_bounds__(64)
scan_fb_kernel(const uint32_t* u01, const uint16_t* __restrict__ u2p,
               const float* __restrict__ x, const float* __restrict__ c0,
               const float* __restrict__ wc, const float* __restrict__ bias,
               float* out)
{
    int cid = blockIdx.x * 64 + threadIdx.x;
    int d = cid & (D_DIM - 1);
    float fw = wc[d], rw = wc[D_DIM + d];
    float fb = bias[d], rb = bias[D_DIM + d];
    float c = c0[cid];
    constexpr int P = 16;
    const int STEP = B_DIM * D_DIM;
    uint32_t b01[P]; uint16_t b2v[P]; float bx[P];
#pragma unroll
    for (int j = 0; j < P; j++) {
        b01[j] = u01[cid + j * STEP]; b2v[j] = u2p[cid + j * STEP]; bx[j] = x[cid + j * STEP];
    }
    for (int lb = 0; lb < L_DIM; lb += P) {
#pragma unroll
        for (int j = 0; j < P; j++) {
            int l = lb + j;
            uint32_t v01 = b01[j];
            uint32_t v23 = (uint32_t)b2v[j] | ((uint32_t)f2bf(bx[j] * SCALE_X) << 16);
            int ln = l + P; if (ln > L_DIM - 1) ln = L_DIM - 1;
            int ri = cid + ln * STEP;
            b01[j] = u01[ri]; b2v[j] = u2p[ri]; bx[j] = x[ri];
            float h; sru_step(v01, v23, fw, rw, fb, rb, c, h);
            out[l * STEP + cid] = h;
        }
    }
    out[L_DIM * STEP + cid] = c;
}

extern "C" void kernel_launch(void* const* d_in, const int* in_sizes, int n_in,
                              void* d_out, int out_size, void* d_ws, size_t ws_size,
                              hipStream_t stream) {
    const float* x    = (const float*)d_in[0];
    const float* c0   = (const float*)d_in[1];
    const float* w    = (const float*)d_in[2];
    const float* wc   = (const float*)d_in[3];
    const float* bias = (const float*)d_in[4];

    const size_t WT_BYTES  = 6291456;       // 6 MB
    const size_t U23_BYTES = 134217728;     // 128 MB
    const size_t XB_BYTES  = 67108864;      // 64 MB

    uint16_t* wt = (uint16_t*)d_ws;
    char* p = (char*)d_ws + WT_BYTES;

    uint16_t* u01 = (uint16_t*)d_out;       // aliases h region of d_out
    float* out = (float*)d_out;

    prep_w_kernel<<<(K_DIM * N_DIM) / 256, 256, 0, stream>>>(w, wt);

    if (ws_size >= WT_BYTES + U23_BYTES + XB_BYTES) {       // proven: ws >= 208 MB
        uint32_t* u23 = (uint32_t*)p;
        uint16_t* xb  = (uint16_t*)(p + U23_BYTES);
        prep_x_kernel<<<(M_DIM * K_DIM / 4) / 256, 256, 0, stream>>>(x, xb, (uint16_t*)u23);
        gemm_kernel<true, true><<<(M_DIM / 128) * (N_DIM / 128), 256, 0, stream>>>(
            x, xb, wt, u01, (uint16_t*)u23);
        scan2_kernel<<<(B_DIM * D_DIM) / 64, 64, 0, stream>>>(
            (const uint32_t*)u01, u23, c0, wc, bias, out);
    } else {                                                // 70 MB fallback
        uint16_t* u2p = (uint16_t*)p;
        gemm_kernel<false, false><<<(M_DIM / 128) * (N_DIM / 128), 256, 0, stream>>>(
            x, nullptr, wt, u01, u2p);
        scan_fb_kernel<<<(B_DIM * D_DIM) / 64, 64, 0, stream>>>(
            (const uint32_t*)u01, u2p, x, c0, wc, bias, out);
    }
}